// Round 9
// baseline (408.939 us; speedup 1.0000x reference)
//
#include <hip/hip_runtime.h>
#include <math.h>

#define NN 50000
#define E0 640000
#define ET 690000   // E0 + NN self loops
#define F1 128
#define D1 256      // 8 heads * 32
#define C2 16
#define NB 196      // ceil(NN/256)
#define MPAD 50048  // 391*128, padded node count for MFMA tiles
#define PADK 136    // 128 + 8 pad (breaks ds_read_b128 bank conflicts)
#define PADK2 264   // 256 + 8 pad for gemm2 B tile
#define LOG2E 1.4426950408889634f

typedef _Float16 f16x8 __attribute__((ext_vector_type(8)));
typedef _Float16 h2 __attribute__((ext_vector_type(2)));
typedef __attribute__((ext_vector_type(4))) float f32x4;

__device__ __forceinline__ unsigned short f2h(float f) {
  union { _Float16 h; unsigned short u; } c;
  c.h = (_Float16)f;
  return c.u;
}
__device__ __forceinline__ float h2f(unsigned short u) {
  union { unsigned short u; _Float16 h; } c; c.u = u; return (float)c.h;
}
__device__ __forceinline__ h2 u2h2(unsigned u) {
  union { unsigned u; h2 h; } c; c.u = u; return c.h;
}
__device__ __forceinline__ unsigned h22u(h2 h) {
  union { h2 h; unsigned u; } c; c.h = h; return c.u;
}

// ---------------- fused prep: cvt_x | cvt_w | hist ----------------
__global__ __launch_bounds__(256) void k_prep(
    const float* __restrict__ x, const float* __restrict__ Wl,
    const float* __restrict__ Wr, const float* __restrict__ W2l,
    const float* __restrict__ W2r, const int* __restrict__ ei,
    unsigned short* __restrict__ xb, unsigned short* __restrict__ wt,
    unsigned short* __restrict__ wt2, int* __restrict__ deg) {
  const int b = blockIdx.x;
  if (b < 6256) {
    long long i = (long long)(b * 256 + threadIdx.x) * 4;
    if (i >= (long long)MPAD * F1) return;
    float4 v = (i < (long long)NN * F1) ? *(const float4*)&x[i]
                                        : make_float4(0.f, 0.f, 0.f, 0.f);
    ushort4 o;
    o.x = f2h(v.x); o.y = f2h(v.y); o.z = f2h(v.z); o.w = f2h(v.w);
    *(ushort4*)&xb[i] = o;
  } else if (b < 6512) {
    int tid = (b - 6256) * 256 + threadIdx.x;   // = n*128 + k
    int n = tid >> 7, k = tid & 127;
    float v = (n < 256) ? Wl[k * 256 + n] : Wr[k * 256 + (n - 256)];
    wt[tid] = f2h(v);
  } else if (b < 6544) {
    int tid = (b - 6512) * 256 + threadIdx.x;   // = n*256 + k
    int n = tid >> 8, k = tid & 255;
    float v = (n < 16) ? W2l[k * 16 + n] : W2r[k * 16 + (n - 16)];
    wt2[tid] = f2h(v);
  } else {
    int e = (b - 6544) * 256 + threadIdx.x;
    if (e >= ET) return;
    int d = (e < E0) ? ei[E0 + e] : (e - E0);
    atomicAdd(&deg[d], 1);
  }
}

// ---------------- Layer-1 GEMM via MFMA (fp16) ----------------
// C[M=50048, N=512] = xb @ Wt^T. Outputs HEAD-MAJOR: out[head][node][32].
__global__ __launch_bounds__(256) void k_gemm1m(
    const unsigned short* __restrict__ xb, const unsigned short* __restrict__ wt,
    unsigned short* __restrict__ xlh, unsigned short* __restrict__ xrh) {
  __shared__ unsigned short Al[128 * PADK];
  __shared__ unsigned short Bl[128 * PADK];
  const int t = threadIdx.x;
  const int m0 = blockIdx.x * 128;
  const int n0 = blockIdx.y * 128;
  {
    const int r = t >> 4;             // 0..15
    const int c = (t & 15) * 8;
#pragma unroll
    for (int p = 0; p < 8; ++p) {
      const int row = r + p * 16;
      *(float4*)&Al[row * PADK + c] = *(const float4*)&xb[(size_t)(m0 + row) * F1 + c];
      *(float4*)&Bl[row * PADK + c] = *(const float4*)&wt[(size_t)(n0 + row) * F1 + c];
    }
  }
  __syncthreads();
  const int wave = t >> 6, lane = t & 63;
  const int mw = (wave >> 1) * 64, nw = (wave & 1) * 64;
  const int fr = lane & 15, fq = lane >> 4;
  f32x4 acc[4][4] = {};
#pragma unroll
  for (int ks = 0; ks < 4; ++ks) {
    const int ko = ks * 32 + fq * 8;
    f16x8 a[4], b[4];
#pragma unroll
    for (int i = 0; i < 4; ++i)
      a[i] = *(const f16x8*)&Al[(mw + i * 16 + fr) * PADK + ko];
#pragma unroll
    for (int j = 0; j < 4; ++j)
      b[j] = *(const f16x8*)&Bl[(nw + j * 16 + fr) * PADK + ko];
#pragma unroll
    for (int i = 0; i < 4; ++i)
#pragma unroll
      for (int j = 0; j < 4; ++j)
        acc[i][j] = __builtin_amdgcn_mfma_f32_16x16x32_f16(a[i], b[j], acc[i][j], 0, 0, 0);
  }
  unsigned short* outp = (n0 < 256) ? xlh : xrh;
  const int cb = (n0 & 255) + nw + fr;
#pragma unroll
  for (int j = 0; j < 4; ++j) {
    const int col = cb + j * 16;
    const int head = col >> 5, f = col & 31;
    unsigned short* hp = outp + (size_t)head * NN * 32 + f;
#pragma unroll
    for (int i = 0; i < 4; ++i) {
      const int gm0 = m0 + mw + i * 16 + fq * 4;
#pragma unroll
      for (int r = 0; r < 4; ++r) {
        const int gm = gm0 + r;
        if (gm < NN) hp[(size_t)gm * 32] = f2h(acc[i][j][r]);
      }
    }
  }
}

// ---------------- CSR scan/scatter ----------------
__global__ __launch_bounds__(256) void k_scan_part(const int* __restrict__ deg,
                                                   int* __restrict__ part) {
  int i = blockIdx.x * 256 + threadIdx.x;
  int v = (i < NN) ? deg[i] : 0;
  v += __shfl_xor(v, 1);  v += __shfl_xor(v, 2);  v += __shfl_xor(v, 4);
  v += __shfl_xor(v, 8);  v += __shfl_xor(v, 16); v += __shfl_xor(v, 32);
  __shared__ int w[4];
  if ((threadIdx.x & 63) == 0) w[threadIdx.x >> 6] = v;
  __syncthreads();
  if (threadIdx.x == 0) part[blockIdx.x] = w[0] + w[1] + w[2] + w[3];
}

__global__ __launch_bounds__(256) void k_scan_top(int* __restrict__ part,
                                                  int* __restrict__ offs) {
  __shared__ int lds[256];
  int t = threadIdx.x;
  int v = (t < NB) ? part[t] : 0;
  lds[t] = v;
  __syncthreads();
  for (int off = 1; off < 256; off <<= 1) {
    int u = (t >= off) ? lds[t - off] : 0;
    __syncthreads();
    lds[t] += u;
    __syncthreads();
  }
  if (t < NB) part[t] = lds[t] - v;
  if (t == 255) offs[NN] = lds[255];
}

__global__ __launch_bounds__(256) void k_scan_apply(int* __restrict__ deg,
                                                    const int* __restrict__ part,
                                                    int* __restrict__ offs) {
  __shared__ int lds[256];
  int t = threadIdx.x;
  int i = blockIdx.x * 256 + t;
  int v = (i < NN) ? deg[i] : 0;
  lds[t] = v;
  __syncthreads();
  for (int off = 1; off < 256; off <<= 1) {
    int u = (t >= off) ? lds[t - off] : 0;
    __syncthreads();
    lds[t] += u;
    __syncthreads();
  }
  int excl = lds[t] - v + part[blockIdx.x];
  if (i < NN) { offs[i] = excl; deg[i] = excl; }  // deg becomes cursor
}

__global__ void k_scatter(const int* __restrict__ ei, int* __restrict__ cur,
                          unsigned short* __restrict__ csr) {
  int e = blockIdx.x * 256 + threadIdx.x;
  if (e >= ET) return;
  int s, d;
  if (e < E0) { s = ei[e]; d = ei[E0 + e]; } else { s = d = e - E0; }
  int pos = atomicAdd(&cur[d], 1);
  csr[pos] = (unsigned short)s;   // node ids < 65536
}

// ---------------- Layer-1 aggregation (per-head waves, XCD-local) ----------------
// One wave per (node, head); head = blockIdx&7 pins each head to one XCD
// (round-robin heuristic) so the 3.2 MB head slice lives in that XCD's L2.
// 16 edge-groups of 4 lanes; group gathers one edge's 64B head slice.
__global__ __launch_bounds__(256) void k_agg1(
    const unsigned short* __restrict__ xlh, const unsigned short* __restrict__ xrh,
    unsigned short* __restrict__ hb,
    const int* __restrict__ offs, const unsigned short* __restrict__ csr,
    const float* __restrict__ att, const float* __restrict__ b1) {
  const int b = blockIdx.x;
  const int head = b & 7;
  const int wave = threadIdx.x >> 6;
  const int n = (b >> 3) * 4 + wave;
  const int lane = threadIdx.x & 63;
  const int g = lane >> 2;          // edge group 0..15
  const int j4 = lane & 3;          // lane within group
  const int colh = j4 * 8;          // feat offset within head
  const int col = head * 32 + colh; // global feat col (att/b1)
  const unsigned short* xlhead = xlh + (size_t)head * NN * 32;

  const uint4 xru = *(const uint4*)&xrh[((size_t)head * NN + n) * 32 + colh];
  h2 xr2[4];
  xr2[0] = u2h2(xru.x); xr2[1] = u2h2(xru.y);
  xr2[2] = u2h2(xru.z); xr2[3] = u2h2(xru.w);
  float at8[8];
  *(float4*)&at8[0] = *(const float4*)&att[col];
  *(float4*)&at8[4] = *(const float4*)&att[col + 4];
  h2 ath6[4], ath4[4];
#pragma unroll
  for (int j = 0; j < 4; ++j) {
    ath6[j] = h2{(_Float16)(at8[2 * j] * (0.6f * LOG2E)),
                 (_Float16)(at8[2 * j + 1] * (0.6f * LOG2E))};
    ath4[j] = h2{(_Float16)(at8[2 * j] * (0.4f * LOG2E)),
                 (_Float16)(at8[2 * j + 1] * (0.4f * LOG2E))};
  }
  float l = 0.f;
  h2 acc2[4] = {h2{0, 0}, h2{0, 0}, h2{0, 0}, h2{0, 0}};
  const int beg = offs[n], fin = offs[n + 1];

  for (int idx = beg + g; idx < fin; idx += 16) {
    const int s = csr[idx];
    const uint4 w = *(const uint4*)&xlhead[(size_t)s * 32 + colh];
    h2 xh[4];
    xh[0] = u2h2(w.x); xh[1] = u2h2(w.y); xh[2] = u2h2(w.z); xh[3] = u2h2(w.w);
    float c = 0.f;
#pragma unroll
    for (int j = 0; j < 4; ++j) {
      h2 v = xh[j] + xr2[j];
      h2 a = u2h2(h22u(v) & 0x7FFF7FFFu);       // |v| per half
      c = __builtin_amdgcn_fdot2(v, ath6[j], c, false);
      c = __builtin_amdgcn_fdot2(a, ath4[j], c, false);
    }
    c += __shfl_xor(c, 1);
    c += __shfl_xor(c, 2);          // sum over the group's 4 lanes (32 feats)
    const float p = exp2f(c);
    l += p;
    const _Float16 ph = (_Float16)p;
    const h2 p2 = h2{ph, ph};
#pragma unroll
    for (int j = 0; j < 4; ++j) acc2[j] += p2 * xh[j];   // v_pk_fma_f16
  }
  // merge the 16 groups (lanes with equal j4 hold the same feats)
  l += __shfl_xor(l, 4);  l += __shfl_xor(l, 8);
  l += __shfl_xor(l, 16); l += __shfl_xor(l, 32);
#pragma unroll
  for (int j = 0; j < 4; ++j) {
    unsigned u = h22u(acc2[j]);
    u = __shfl_xor((int)u, 4);  acc2[j] += u2h2(u);
    u = h22u(acc2[j]); u = __shfl_xor((int)u, 8);  acc2[j] += u2h2(u);
    u = h22u(acc2[j]); u = __shfl_xor((int)u, 16); acc2[j] += u2h2(u);
    u = h22u(acc2[j]); u = __shfl_xor((int)u, 32); acc2[j] += u2h2(u);
  }
  if (g == 0) {
    const float rl = 1.f / (l + 1e-16f);
    float b8[8], o[8];
    *(float4*)&b8[0] = *(const float4*)&b1[col];
    *(float4*)&b8[4] = *(const float4*)&b1[col + 4];
#pragma unroll
    for (int j = 0; j < 4; ++j) {
      o[2 * j]     = (float)acc2[j][0] * rl + b8[2 * j];
      o[2 * j + 1] = (float)acc2[j][1] * rl + b8[2 * j + 1];
    }
#pragma unroll
    for (int k = 0; k < 8; ++k) o[k] = o[k] > 0.f ? o[k] : expm1f(o[k]);
    ushort4 p0, p1;
    p0.x = f2h(o[0]); p0.y = f2h(o[1]); p0.z = f2h(o[2]); p0.w = f2h(o[3]);
    p1.x = f2h(o[4]); p1.y = f2h(o[5]); p1.z = f2h(o[6]); p1.w = f2h(o[7]);
    *(uint2*)&hb[(size_t)n * D1 + col] = *(uint2*)&p0;
    *(uint2*)&hb[(size_t)n * D1 + col + 4] = *(uint2*)&p1;
  }
}

// ---------------- Layer-2 GEMM via MFMA (fp16) ----------------
// h2[50000, 32] = hb @ Wt2^T. h2l stored fp16 (gathered), h2r fp32.
__global__ __launch_bounds__(256) void k_gemm2m(
    const unsigned short* __restrict__ hb, const unsigned short* __restrict__ wt2,
    unsigned short* __restrict__ h2lh, float* __restrict__ h2r) {
  __shared__ unsigned short Bl[32 * PADK2];
  const int t = threadIdx.x;
  {
    const int n = t >> 3, k0 = (t & 7) * 32;
#pragma unroll
    for (int j = 0; j < 4; ++j)
      *(uint4*)&Bl[n * PADK2 + k0 + j * 8] = *(const uint4*)&wt2[n * 256 + k0 + j * 8];
  }
  __syncthreads();
  const int wave = t >> 6, lane = t & 63;
  const int fr = lane & 15, fq = lane >> 4;
  const int m0 = blockIdx.x * 128 + wave * 32;
  f32x4 acc[2][2] = {};
#pragma unroll
  for (int ks = 0; ks < 8; ++ks) {
    const int ko = ks * 32 + fq * 8;
    f16x8 a[2], b[2];
#pragma unroll
    for (int i = 0; i < 2; ++i) {
      int row = m0 + i * 16 + fr; if (row >= NN) row = NN - 1;
      a[i] = *(const f16x8*)&hb[(size_t)row * D1 + ko];
    }
#pragma unroll
    for (int j = 0; j < 2; ++j)
      b[j] = *(const f16x8*)&Bl[(j * 16 + fr) * PADK2 + ko];
#pragma unroll
    for (int i = 0; i < 2; ++i)
#pragma unroll
      for (int j = 0; j < 2; ++j)
        acc[i][j] = __builtin_amdgcn_mfma_f32_16x16x32_f16(a[i], b[j], acc[i][j], 0, 0, 0);
  }
#pragma unroll
  for (int i = 0; i < 2; ++i) {
    const int gm0 = m0 + i * 16 + fq * 4;
#pragma unroll
    for (int r = 0; r < 4; ++r) {
      const int gm = gm0 + r;
      if (gm < NN) {
        h2lh[(size_t)gm * C2 + fr] = f2h(acc[i][0][r]);
        h2r[(size_t)gm * C2 + fr] = acc[i][1][r];
      }
    }
  }
}

// ---------------- Layer-2 aggregation ----------------
__global__ __launch_bounds__(256) void k_agg2(
    const unsigned short* __restrict__ h2lh, const float* __restrict__ h2r,
    const int* __restrict__ offs, const unsigned short* __restrict__ csr,
    const float* __restrict__ att2, const float* __restrict__ b2,
    float* __restrict__ out) {
  const int wave = threadIdx.x >> 6;
  const int lane = threadIdx.x & 63;
  const int n = blockIdx.x * 4 + wave;
  if (n >= NN) return;
  const int c = lane & 15, g = lane >> 4;
  const float xr_v = h2r[(size_t)n * C2 + c];
  const float att_v = att2[c] * LOG2E;
  float l = 0.f, acc = 0.f;
  const int beg = offs[n], fin = offs[n + 1];
  for (int idx = beg + g; idx < fin; idx += 4) {
    int s = csr[idx];
    float xlv = h2f(h2lh[(size_t)s * C2 + c]);
    float v = xlv + xr_v;
    v = fmaxf(v, 0.2f * v);
    float sc0 = v * att_v;
    sc0 += __shfl_xor(sc0, 1);
    sc0 += __shfl_xor(sc0, 2);
    sc0 += __shfl_xor(sc0, 4);
    sc0 += __shfl_xor(sc0, 8);
    float p = exp2f(sc0);
    l += p;
    acc = fmaf(p, xlv, acc);
  }
  l += __shfl_xor(l, 16);   l += __shfl_xor(l, 32);
  acc += __shfl_xor(acc, 16); acc += __shfl_xor(acc, 32);
  float o = acc / (l + 1e-16f) + b2[c];
  o = o > 0.f ? o : 0.01f * o;
  if (lane < 16) out[(size_t)n * C2 + c] = o;
}

extern "C" void kernel_launch(void* const* d_in, const int* in_sizes, int n_in,
                              void* d_out, int out_size, void* d_ws, size_t ws_size,
                              hipStream_t stream) {
  const float* x    = (const float*)d_in[0];
  const int*   ei   = (const int*)d_in[1];
  const float* W1l  = (const float*)d_in[2];
  const float* W1r  = (const float*)d_in[3];
  const float* att1 = (const float*)d_in[4];
  const float* b1   = (const float*)d_in[5];
  const float* W2l  = (const float*)d_in[6];
  const float* W2r  = (const float*)d_in[7];
  const float* att2 = (const float*)d_in[8];
  const float* b2   = (const float*)d_in[9];
  float* out = (float*)d_out;

  // Workspace layout (~93 MB):
  unsigned short* xlh = (unsigned short*)d_ws;        // [8][NN][32] fp16
  unsigned short* xrh = xlh + (size_t)NN * D1;        // [8][NN][32] fp16
  unsigned short* hb  = xrh + (size_t)NN * D1;        // [NN][256] fp16
  int* deg  = (int*)(hb + (size_t)NN * D1);           // NN (becomes cursor)
  int* offs = deg + NN;                               // NN+1
  unsigned short* csr = (unsigned short*)(offs + NN + 1);  // ET u16
  int* part = (int*)(csr + ET + 2);                   // NB
  unsigned short* xb = (unsigned short*)(part + NB);  // MPAD*F1 fp16
  unsigned short* wt = xb + (size_t)MPAD * F1;        // 512*128 fp16
  unsigned short* wt2 = wt + 512 * F1;                // 32*256 fp16
  unsigned short* h2lh = xlh;                         // alias: xlh dead after agg1
  float* h2r = (float*)(h2lh + (size_t)NN * C2);

  hipMemsetAsync(deg, 0, NN * sizeof(int), stream);
  k_prep<<<6544 + (ET + 255) / 256, 256, 0, stream>>>(
      x, W1l, W1r, W2l, W2r, ei, xb, wt, wt2, deg);
  k_gemm1m<<<dim3(MPAD / 128, 4), 256, 0, stream>>>(xb, wt, xlh, xrh);
  k_scan_part<<<NB, 256, 0, stream>>>(deg, part);
  k_scan_top<<<1, 256, 0, stream>>>(part, offs);
  k_scan_apply<<<NB, 256, 0, stream>>>(deg, part, offs);
  k_scatter<<<(ET + 255) / 256, 256, 0, stream>>>(ei, deg, csr);
  k_agg1<<<(NN / 4) * 8, 256, 0, stream>>>(xlh, xrh, hb, offs, csr, att1, b1);
  k_gemm2m<<<(NN + 127) / 128, 256, 0, stream>>>(hb, wt2, h2lh, h2r);
  k_agg2<<<NN / 4, 256, 0, stream>>>(h2lh, h2r, offs, csr, att2, b2, out);
}

// Round 10
// 271.879 us; speedup vs baseline: 1.5041x; 1.5041x over previous
//
#include <hip/hip_runtime.h>
#include <math.h>

#define NN 50000
#define E0 640000
#define ET 690000   // E0 + NN self loops
#define F1 128
#define D1 256      // 8 heads * 32
#define C2 16
#define NB 196      // ceil(NN/256)
#define MPAD 50048  // 391*128, padded node count for MFMA tiles
#define PADK 136    // 128 + 8 pad (breaks ds_read_b128 bank conflicts)
#define PADK2 264   // 256 + 8 pad for gemm2 B tile
#define LOG2E 1.4426950408889634f
#define NBK1 782    // ceil(NN/64) node-blocks for agg1

typedef _Float16 f16x8 __attribute__((ext_vector_type(8)));
typedef _Float16 h2 __attribute__((ext_vector_type(2)));
typedef __attribute__((ext_vector_type(4))) float f32x4;

__device__ __forceinline__ unsigned short f2h(float f) {
  union { _Float16 h; unsigned short u; } c;
  c.h = (_Float16)f;
  return c.u;
}
__device__ __forceinline__ float h2f(unsigned short u) {
  union { unsigned short u; _Float16 h; } c; c.u = u; return (float)c.h;
}
__device__ __forceinline__ h2 u2h2(unsigned u) {
  union { unsigned u; h2 h; } c; c.u = u; return c.h;
}
__device__ __forceinline__ unsigned h22u(h2 h) {
  union { h2 h; unsigned u; } c; c.h = h; return c.u;
}

// ---------------- fused prep: cvt_x | cvt_w | hist ----------------
__global__ __launch_bounds__(256) void k_prep(
    const float* __restrict__ x, const float* __restrict__ Wl,
    const float* __restrict__ Wr, const float* __restrict__ W2l,
    const float* __restrict__ W2r, const int* __restrict__ ei,
    unsigned short* __restrict__ xb, unsigned short* __restrict__ wt,
    unsigned short* __restrict__ wt2, int* __restrict__ deg) {
  const int b = blockIdx.x;
  if (b < 6256) {
    long long i = (long long)(b * 256 + threadIdx.x) * 4;
    if (i >= (long long)MPAD * F1) return;
    float4 v = (i < (long long)NN * F1) ? *(const float4*)&x[i]
                                        : make_float4(0.f, 0.f, 0.f, 0.f);
    ushort4 o;
    o.x = f2h(v.x); o.y = f2h(v.y); o.z = f2h(v.z); o.w = f2h(v.w);
    *(ushort4*)&xb[i] = o;
  } else if (b < 6512) {
    int tid = (b - 6256) * 256 + threadIdx.x;   // = n*128 + k
    int n = tid >> 7, k = tid & 127;
    float v = (n < 256) ? Wl[k * 256 + n] : Wr[k * 256 + (n - 256)];
    wt[tid] = f2h(v);
  } else if (b < 6544) {
    int tid = (b - 6512) * 256 + threadIdx.x;   // = n*256 + k
    int n = tid >> 8, k = tid & 255;
    float v = (n < 16) ? W2l[k * 16 + n] : W2r[k * 16 + (n - 16)];
    wt2[tid] = f2h(v);
  } else {
    int e = (b - 6544) * 256 + threadIdx.x;
    if (e >= ET) return;
    int d = (e < E0) ? ei[E0 + e] : (e - E0);
    atomicAdd(&deg[d], 1);
  }
}

// ---------------- Layer-1 GEMM via MFMA (fp16) ----------------
// C[M=50048, N=512] = xb @ Wt^T. Outputs HEAD-MAJOR: out[head][node][32].
__global__ __launch_bounds__(256) void k_gemm1m(
    const unsigned short* __restrict__ xb, const unsigned short* __restrict__ wt,
    unsigned short* __restrict__ xlh, unsigned short* __restrict__ xrh) {
  __shared__ unsigned short Al[128 * PADK];
  __shared__ unsigned short Bl[128 * PADK];
  const int t = threadIdx.x;
  const int m0 = blockIdx.x * 128;
  const int n0 = blockIdx.y * 128;
  {
    const int r = t >> 4;             // 0..15
    const int c = (t & 15) * 8;
#pragma unroll
    for (int p = 0; p < 8; ++p) {
      const int row = r + p * 16;
      *(float4*)&Al[row * PADK + c] = *(const float4*)&xb[(size_t)(m0 + row) * F1 + c];
      *(float4*)&Bl[row * PADK + c] = *(const float4*)&wt[(size_t)(n0 + row) * F1 + c];
    }
  }
  __syncthreads();
  const int wave = t >> 6, lane = t & 63;
  const int mw = (wave >> 1) * 64, nw = (wave & 1) * 64;
  const int fr = lane & 15, fq = lane >> 4;
  f32x4 acc[4][4] = {};
#pragma unroll
  for (int ks = 0; ks < 4; ++ks) {
    const int ko = ks * 32 + fq * 8;
    f16x8 a[4], b[4];
#pragma unroll
    for (int i = 0; i < 4; ++i)
      a[i] = *(const f16x8*)&Al[(mw + i * 16 + fr) * PADK + ko];
#pragma unroll
    for (int j = 0; j < 4; ++j)
      b[j] = *(const f16x8*)&Bl[(nw + j * 16 + fr) * PADK + ko];
#pragma unroll
    for (int i = 0; i < 4; ++i)
#pragma unroll
      for (int j = 0; j < 4; ++j)
        acc[i][j] = __builtin_amdgcn_mfma_f32_16x16x32_f16(a[i], b[j], acc[i][j], 0, 0, 0);
  }
  unsigned short* outp = (n0 < 256) ? xlh : xrh;
  const int cb = (n0 & 255) + nw + fr;
#pragma unroll
  for (int j = 0; j < 4; ++j) {
    const int col = cb + j * 16;
    const int head = col >> 5, f = col & 31;
    unsigned short* hp = outp + (size_t)head * NN * 32 + f;
#pragma unroll
    for (int i = 0; i < 4; ++i) {
      const int gm0 = m0 + mw + i * 16 + fq * 4;
#pragma unroll
      for (int r = 0; r < 4; ++r) {
        const int gm = gm0 + r;
        if (gm < NN) hp[(size_t)gm * 32] = f2h(acc[i][j][r]);
      }
    }
  }
}

// ---------------- CSR scan/scatter ----------------
__global__ __launch_bounds__(256) void k_scan_part(const int* __restrict__ deg,
                                                   int* __restrict__ part) {
  int i = blockIdx.x * 256 + threadIdx.x;
  int v = (i < NN) ? deg[i] : 0;
  v += __shfl_xor(v, 1);  v += __shfl_xor(v, 2);  v += __shfl_xor(v, 4);
  v += __shfl_xor(v, 8);  v += __shfl_xor(v, 16); v += __shfl_xor(v, 32);
  __shared__ int w[4];
  if ((threadIdx.x & 63) == 0) w[threadIdx.x >> 6] = v;
  __syncthreads();
  if (threadIdx.x == 0) part[blockIdx.x] = w[0] + w[1] + w[2] + w[3];
}

__global__ __launch_bounds__(256) void k_scan_top(int* __restrict__ part,
                                                  int* __restrict__ offs) {
  __shared__ int lds[256];
  int t = threadIdx.x;
  int v = (t < NB) ? part[t] : 0;
  lds[t] = v;
  __syncthreads();
  for (int off = 1; off < 256; off <<= 1) {
    int u = (t >= off) ? lds[t - off] : 0;
    __syncthreads();
    lds[t] += u;
    __syncthreads();
  }
  if (t < NB) part[t] = lds[t] - v;
  if (t == 255) offs[NN] = lds[255];
}

__global__ __launch_bounds__(256) void k_scan_apply(int* __restrict__ deg,
                                                    const int* __restrict__ part,
                                                    int* __restrict__ offs) {
  __shared__ int lds[256];
  int t = threadIdx.x;
  int i = blockIdx.x * 256 + t;
  int v = (i < NN) ? deg[i] : 0;
  lds[t] = v;
  __syncthreads();
  for (int off = 1; off < 256; off <<= 1) {
    int u = (t >= off) ? lds[t - off] : 0;
    __syncthreads();
    lds[t] += u;
    __syncthreads();
  }
  int excl = lds[t] - v + part[blockIdx.x];
  if (i < NN) { offs[i] = excl; deg[i] = excl; }  // deg becomes cursor
}

__global__ void k_scatter(const int* __restrict__ ei, int* __restrict__ cur,
                          unsigned short* __restrict__ csr) {
  int e = blockIdx.x * 256 + threadIdx.x;
  if (e >= ET) return;
  int s, d;
  if (e < E0) { s = ei[e]; d = ei[E0 + e]; } else { s = d = e - E0; }
  int pos = atomicAdd(&cur[d], 1);
  csr[pos] = (unsigned short)s;   // node ids < 65536
}

// ---------------- Layer-1 aggregation (head-pinned, 16 nodes/wave) ----------------
// head = blockIdx&7 pins each head's 3.2 MB slice to one XCD L2 (round-robin
// heuristic, validated R9: FETCH 165->48 MB). One wave = 16 nodes x 1 head;
// each 4-lane group owns one node's edge loop. Per edge: group gathers one
// contiguous 64B line, 2 intra-group shuffles; p identical across group ->
// no epilogue reduction. 2x edge unroll for independent fdot2 chains.
__global__ __launch_bounds__(256) void k_agg1(
    const unsigned short* __restrict__ xlh, const unsigned short* __restrict__ xrh,
    unsigned short* __restrict__ hb,
    const int* __restrict__ offs, const unsigned short* __restrict__ csr,
    const float* __restrict__ att, const float* __restrict__ b1) {
  const int b = blockIdx.x;
  const int head = b & 7;
  const int wave = threadIdx.x >> 6;
  const int lane = threadIdx.x & 63;
  const int g = lane >> 2;          // node group 0..15
  const int j4 = lane & 3;          // lane within group
  const int n = (b >> 3) * 64 + wave * 16 + g;
  const bool valid = n < NN;
  const int colh = j4 * 8;          // feat offset within head
  const int col = head * 32 + colh; // global feat col (att/b1)
  const unsigned short* xlhead = xlh + (size_t)head * NN * 32;

  const int nc = valid ? n : 0;
  const uint4 xru = *(const uint4*)&xrh[((size_t)head * NN + nc) * 32 + colh];
  h2 xr2[4];
  xr2[0] = u2h2(xru.x); xr2[1] = u2h2(xru.y);
  xr2[2] = u2h2(xru.z); xr2[3] = u2h2(xru.w);
  float at8[8];
  *(float4*)&at8[0] = *(const float4*)&att[col];
  *(float4*)&at8[4] = *(const float4*)&att[col + 4];
  h2 ath6[4], ath4[4];
#pragma unroll
  for (int j = 0; j < 4; ++j) {
    ath6[j] = h2{(_Float16)(at8[2 * j] * (0.6f * LOG2E)),
                 (_Float16)(at8[2 * j + 1] * (0.6f * LOG2E))};
    ath4[j] = h2{(_Float16)(at8[2 * j] * (0.4f * LOG2E)),
                 (_Float16)(at8[2 * j + 1] * (0.4f * LOG2E))};
  }
  float l = 0.f;
  h2 acc2[4] = {h2{0, 0}, h2{0, 0}, h2{0, 0}, h2{0, 0}};
  const int beg = valid ? offs[n] : 0;
  const int fin = valid ? offs[n + 1] : 0;

  auto score = [&](const h2* xh) -> float {
    float cv = 0.f, ca = 0.f;
#pragma unroll
    for (int j = 0; j < 4; ++j) {
      h2 v = xh[j] + xr2[j];
      h2 a = u2h2(h22u(v) & 0x7FFF7FFFu);       // |v| per half
      cv = __builtin_amdgcn_fdot2(v, ath6[j], cv, false);
      ca = __builtin_amdgcn_fdot2(a, ath4[j], ca, false);
    }
    float c = cv + ca;
    c += __shfl_xor(c, 1);
    c += __shfl_xor(c, 2);          // sum over the group's 4 lanes (32 feats)
    return c;
  };

  int idx = beg;
  for (; idx + 1 < fin; idx += 2) {
    const int s0 = csr[idx], s1 = csr[idx + 1];
    const uint4 w0 = *(const uint4*)&xlhead[(size_t)s0 * 32 + colh];
    const uint4 w1 = *(const uint4*)&xlhead[(size_t)s1 * 32 + colh];
    h2 xh0[4], xh1[4];
    xh0[0] = u2h2(w0.x); xh0[1] = u2h2(w0.y); xh0[2] = u2h2(w0.z); xh0[3] = u2h2(w0.w);
    xh1[0] = u2h2(w1.x); xh1[1] = u2h2(w1.y); xh1[2] = u2h2(w1.z); xh1[3] = u2h2(w1.w);
    const float c0 = score(xh0);
    const float c1 = score(xh1);
    const float p0 = exp2f(c0), p1 = exp2f(c1);
    l += p0 + p1;
    const _Float16 p0h = (_Float16)p0, p1h = (_Float16)p1;
    const h2 p02 = h2{p0h, p0h}, p12 = h2{p1h, p1h};
#pragma unroll
    for (int j = 0; j < 4; ++j) acc2[j] += p02 * xh0[j] + p12 * xh1[j];
  }
  if (idx < fin) {
    const int s0 = csr[idx];
    const uint4 w0 = *(const uint4*)&xlhead[(size_t)s0 * 32 + colh];
    h2 xh0[4];
    xh0[0] = u2h2(w0.x); xh0[1] = u2h2(w0.y); xh0[2] = u2h2(w0.z); xh0[3] = u2h2(w0.w);
    const float c0 = score(xh0);
    const float p0 = exp2f(c0);
    l += p0;
    const _Float16 p0h = (_Float16)p0;
    const h2 p02 = h2{p0h, p0h};
#pragma unroll
    for (int j = 0; j < 4; ++j) acc2[j] += p02 * xh0[j];
  }
  // l and p were group-uniform -> no cross-lane reduction needed.
  if (valid) {
    const float rl = 1.f / (l + 1e-16f);
    float b8[8], o[8];
    *(float4*)&b8[0] = *(const float4*)&b1[col];
    *(float4*)&b8[4] = *(const float4*)&b1[col + 4];
#pragma unroll
    for (int j = 0; j < 4; ++j) {
      o[2 * j]     = (float)acc2[j][0] * rl + b8[2 * j];
      o[2 * j + 1] = (float)acc2[j][1] * rl + b8[2 * j + 1];
    }
#pragma unroll
    for (int k = 0; k < 8; ++k) o[k] = o[k] > 0.f ? o[k] : expm1f(o[k]);
    ushort4 p;
    p.x = f2h(o[0]); p.y = f2h(o[1]); p.z = f2h(o[2]); p.w = f2h(o[3]);
    ushort4 q;
    q.x = f2h(o[4]); q.y = f2h(o[5]); q.z = f2h(o[6]); q.w = f2h(o[7]);
    uint4 packed;
    packed.x = *(unsigned*)&p.x; packed.y = *(unsigned*)&p.z;
    packed.z = *(unsigned*)&q.x; packed.w = *(unsigned*)&q.z;
    *(uint4*)&hb[(size_t)n * D1 + col] = packed;
  }
}

// ---------------- Layer-2 GEMM via MFMA (fp16) ----------------
// h2[50000, 32] = hb @ Wt2^T. h2l stored fp16 (gathered), h2r fp32.
__global__ __launch_bounds__(256) void k_gemm2m(
    const unsigned short* __restrict__ hb, const unsigned short* __restrict__ wt2,
    unsigned short* __restrict__ h2lh, float* __restrict__ h2r) {
  __shared__ unsigned short Bl[32 * PADK2];
  const int t = threadIdx.x;
  {
    const int n = t >> 3, k0 = (t & 7) * 32;
#pragma unroll
    for (int j = 0; j < 4; ++j)
      *(uint4*)&Bl[n * PADK2 + k0 + j * 8] = *(const uint4*)&wt2[n * 256 + k0 + j * 8];
  }
  __syncthreads();
  const int wave = t >> 6, lane = t & 63;
  const int fr = lane & 15, fq = lane >> 4;
  const int m0 = blockIdx.x * 128 + wave * 32;
  f32x4 acc[2][2] = {};
#pragma unroll
  for (int ks = 0; ks < 8; ++ks) {
    const int ko = ks * 32 + fq * 8;
    f16x8 a[2], b[2];
#pragma unroll
    for (int i = 0; i < 2; ++i) {
      int row = m0 + i * 16 + fr; if (row >= NN) row = NN - 1;
      a[i] = *(const f16x8*)&hb[(size_t)row * D1 + ko];
    }
#pragma unroll
    for (int j = 0; j < 2; ++j)
      b[j] = *(const f16x8*)&Bl[(j * 16 + fr) * PADK2 + ko];
#pragma unroll
    for (int i = 0; i < 2; ++i)
#pragma unroll
      for (int j = 0; j < 2; ++j)
        acc[i][j] = __builtin_amdgcn_mfma_f32_16x16x32_f16(a[i], b[j], acc[i][j], 0, 0, 0);
  }
#pragma unroll
  for (int i = 0; i < 2; ++i) {
    const int gm0 = m0 + i * 16 + fq * 4;
#pragma unroll
    for (int r = 0; r < 4; ++r) {
      const int gm = gm0 + r;
      if (gm < NN) {
        h2lh[(size_t)gm * C2 + fr] = f2h(acc[i][0][r]);
        h2r[(size_t)gm * C2 + fr] = acc[i][1][r];
      }
    }
  }
}

// ---------------- Layer-2 aggregation ----------------
__global__ __launch_bounds__(256) void k_agg2(
    const unsigned short* __restrict__ h2lh, const float* __restrict__ h2r,
    const int* __restrict__ offs, const unsigned short* __restrict__ csr,
    const float* __restrict__ att2, const float* __restrict__ b2,
    float* __restrict__ out) {
  const int wave = threadIdx.x >> 6;
  const int lane = threadIdx.x & 63;
  const int n = blockIdx.x * 4 + wave;
  if (n >= NN) return;
  const int c = lane & 15, g = lane >> 4;
  const float xr_v = h2r[(size_t)n * C2 + c];
  const float att_v = att2[c] * LOG2E;
  float l = 0.f, acc = 0.f;
  const int beg = offs[n], fin = offs[n + 1];
  for (int idx = beg + g; idx < fin; idx += 4) {
    int s = csr[idx];
    float xlv = h2f(h2lh[(size_t)s * C2 + c]);
    float v = xlv + xr_v;
    v = fmaxf(v, 0.2f * v);
    float sc0 = v * att_v;
    sc0 += __shfl_xor(sc0, 1);
    sc0 += __shfl_xor(sc0, 2);
    sc0 += __shfl_xor(sc0, 4);
    sc0 += __shfl_xor(sc0, 8);
    float p = exp2f(sc0);
    l += p;
    acc = fmaf(p, xlv, acc);
  }
  l += __shfl_xor(l, 16);   l += __shfl_xor(l, 32);
  acc += __shfl_xor(acc, 16); acc += __shfl_xor(acc, 32);
  float o = acc / (l + 1e-16f) + b2[c];
  o = o > 0.f ? o : 0.01f * o;
  if (lane < 16) out[(size_t)n * C2 + c] = o;
}

extern "C" void kernel_launch(void* const* d_in, const int* in_sizes, int n_in,
                              void* d_out, int out_size, void* d_ws, size_t ws_size,
                              hipStream_t stream) {
  const float* x    = (const float*)d_in[0];
  const int*   ei   = (const int*)d_in[1];
  const float* W1l  = (const float*)d_in[2];
  const float* W1r  = (const float*)d_in[3];
  const float* att1 = (const float*)d_in[4];
  const float* b1   = (const float*)d_in[5];
  const float* W2l  = (const float*)d_in[6];
  const float* W2r  = (const float*)d_in[7];
  const float* att2 = (const float*)d_in[8];
  const float* b2   = (const float*)d_in[9];
  float* out = (float*)d_out;

  // Workspace layout (~93 MB):
  unsigned short* xlh = (unsigned short*)d_ws;        // [8][NN][32] fp16
  unsigned short* xrh = xlh + (size_t)NN * D1;        // [8][NN][32] fp16
  unsigned short* hb  = xrh + (size_t)NN * D1;        // [NN][256] fp16
  int* deg  = (int*)(hb + (size_t)NN * D1);           // NN (becomes cursor)
  int* offs = deg + NN;                               // NN+1
  unsigned short* csr = (unsigned short*)(offs + NN + 1);  // ET u16
  int* part = (int*)(csr + ET + 2);                   // NB
  unsigned short* xb = (unsigned short*)(part + NB);  // MPAD*F1 fp16
  unsigned short* wt = xb + (size_t)MPAD * F1;        // 512*128 fp16
  unsigned short* wt2 = wt + 512 * F1;                // 32*256 fp16
  unsigned short* h2lh = xlh;                         // alias: xlh dead after agg1
  float* h2r = (float*)(h2lh + (size_t)NN * C2);

  hipMemsetAsync(deg, 0, NN * sizeof(int), stream);
  k_prep<<<6544 + (ET + 255) / 256, 256, 0, stream>>>(
      x, W1l, W1r, W2l, W2r, ei, xb, wt, wt2, deg);
  k_gemm1m<<<dim3(MPAD / 128, 4), 256, 0, stream>>>(xb, wt, xlh, xrh);
  k_scan_part<<<NB, 256, 0, stream>>>(deg, part);
  k_scan_top<<<1, 256, 0, stream>>>(part, offs);
  k_scan_apply<<<NB, 256, 0, stream>>>(deg, part, offs);
  k_scatter<<<(ET + 255) / 256, 256, 0, stream>>>(ei, deg, csr);
  k_agg1<<<NBK1 * 8, 256, 0, stream>>>(xlh, xrh, hb, offs, csr, att1, b1);
  k_gemm2m<<<(NN + 127) / 128, 256, 0, stream>>>(hb, wt2, h2lh, h2r);
  k_agg2<<<NN / 4, 256, 0, stream>>>(h2lh, h2r, offs, csr, att2, b2, out);
}